// Round 2
// baseline (1523.951 us; speedup 1.0000x reference)
//
#include <hip/hip_runtime.h>
#include <hip/hip_bf16.h>

#define N_ 4
#define L_ 1024
#define E_ 1024
#define H_ 32
#define HD_ 32

// ---------------------------------------------------------------------------
// Kernel 1: per-head projections q,k,v.
// grid (L/64, H, N), block 256.
// out layout: (N, H, L, HD) fp32 in workspace.
// ---------------------------------------------------------------------------
__global__ __launch_bounds__(256) void proj_kernel(
    const float* __restrict__ v_in, const float* __restrict__ k_in,
    const float* __restrict__ q_in,
    const float* __restrict__ Wv, const float* __restrict__ Wk,
    const float* __restrict__ Wq,
    float* __restrict__ v_ws, float* __restrict__ k_ws,
    float* __restrict__ q_ws)
{
    const int TOK = 64;
    const int n = blockIdx.z, h = blockIdx.y, l0 = blockIdx.x * TOK;
    const int t = threadIdx.x;

    __shared__ float sW[3][HD_ * (HD_ + 1)];  // row stride 33: bank-conflict-free
    __shared__ float sX[TOK][HD_];

    for (int i = t; i < HD_ * HD_; i += 256) {
        int d = i >> 5, e = i & 31;
        sW[0][d * 33 + e] = Wv[i];
        sW[1][d * 33 + e] = Wk[i];
        sW[2][d * 33 + e] = Wq[i];
    }

    const float* ins[3]  = {v_in, k_in, q_in};
    float*       outs[3] = {v_ws, k_ws, q_ws};

    for (int w = 0; w < 3; ++w) {
        __syncthreads();
        // stage 64 tokens x 32 features of this head
        for (int i = t; i < TOK * HD_; i += 256) {
            int tok = i >> 5, e = i & 31;
            sX[tok][e] = ins[w][(size_t)(n * L_ + l0 + tok) * E_ + h * HD_ + e];
        }
        __syncthreads();
        // y[tok][d] = sum_e x[tok][e] * W[d][e]
        for (int i = t; i < TOK * HD_; i += 256) {
            int tok = i >> 5, d = i & 31;
            float acc = 0.f;
#pragma unroll
            for (int e = 0; e < HD_; ++e)
                acc += sX[tok][e] * sW[w][d * 33 + e];
            outs[w][((size_t)(n * H_ + h) * L_ + l0 + tok) * HD_ + d] = acc;
        }
    }
}

// ---------------------------------------------------------------------------
// Kernel 2: attention for one (n, h, 8-query tile).
// grid (L/8, H, N), block 256. Scores held fully in LDS (8 x 1024 fp32).
// Writes attention output in (N, L, E) fp32 layout (ready for out-proj GEMM).
// ---------------------------------------------------------------------------
#define TQ 8
__global__ __launch_bounds__(256) void attn_kernel(
    const float* __restrict__ q_ws, const float* __restrict__ k_ws,
    const float* __restrict__ v_ws, const int* __restrict__ mask,
    float* __restrict__ x_ws)
{
    const int n = blockIdx.z, h = blockIdx.y, q0 = blockIdx.x * TQ;
    const int t = threadIdx.x;

    __shared__ float sQ[TQ][HD_ + 1];
    __shared__ float sKV[64][HD_ + 1];
    __shared__ float sS[TQ][L_];

    const size_t base = (size_t)(n * H_ + h) * L_;
    const float scale = 0.03125f;  // 1/sqrt(1024)

    // load Q tile
    for (int i = t; i < TQ * HD_; i += 256) {
        int q = i >> 5, e = i & 31;
        sQ[q][e] = q_ws[(base + q0 + q) * HD_ + e];
    }
    __syncthreads();

    // ---- scores: S[q][k] ----
    const int k  = t & 63;
    const int qb = t >> 6;  // 0..3, wave-uniform
    // hoist the two Q rows this thread uses into registers (qb is wave-uniform,
    // so these are LDS broadcasts done once instead of per-k-tile)
    float qr0[HD_], qr1[HD_];
#pragma unroll
    for (int e = 0; e < HD_; ++e) { qr0[e] = sQ[qb][e]; qr1[e] = sQ[qb + 4][e]; }

    for (int c = 0; c < L_ / 64; ++c) {
        __syncthreads();
        for (int i = t; i < 64 * HD_; i += 256) {
            int r = i >> 5, e = i & 31;
            sKV[r][e] = k_ws[(base + c * 64 + r) * HD_ + e];
        }
        __syncthreads();
        const int m = mask[n * L_ + c * 64 + k];
        float acc0 = 0.f, acc1 = 0.f;
#pragma unroll
        for (int e = 0; e < HD_; ++e) {
            float kv = sKV[k][e];
            acc0 += qr0[e] * kv;
            acc1 += qr1[e] * kv;
        }
        float s0 = (m == 0) ? -1e20f : acc0;
        float s1 = (m == 0) ? -1e20f : acc1;
        sS[qb][c * 64 + k]     = s0 * scale;
        sS[qb + 4][c * 64 + k] = s1 * scale;
    }
    __syncthreads();

    // ---- softmax over each row (one wave handles 2 rows) ----
    const int wave = t >> 6, lane = t & 63;
    for (int r = wave * 2; r < wave * 2 + 2; ++r) {
        float mx = -3.4e38f;
        for (int i = lane; i < L_; i += 64) mx = fmaxf(mx, sS[r][i]);
#pragma unroll
        for (int off = 32; off > 0; off >>= 1) mx = fmaxf(mx, __shfl_xor(mx, off, 64));
        float sum = 0.f;
        for (int i = lane; i < L_; i += 64) {
            float e = __expf(sS[r][i] - mx);
            sS[r][i] = e;
            sum += e;
        }
#pragma unroll
        for (int off = 32; off > 0; off >>= 1) sum += __shfl_xor(sum, off, 64);
        float inv = 1.f / sum;
        for (int i = lane; i < L_; i += 64) sS[r][i] *= inv;
    }

    // ---- PV: out[q][d] = sum_l S[q][l] * V[l][d] ----
    const int d = t & 31;
    const int q = t >> 5;  // 0..7
    float acc = 0.f;
    for (int c = 0; c < L_ / 64; ++c) {
        __syncthreads();
        for (int i = t; i < 64 * HD_; i += 256) {
            int r = i >> 5, e = i & 31;
            sKV[r][e] = v_ws[(base + c * 64 + r) * HD_ + e];
        }
        __syncthreads();
#pragma unroll
        for (int l = 0; l < 64; ++l)
            acc += sS[q][c * 64 + l] * sKV[l][d];
    }
    x_ws[(size_t)(n * L_ + q0 + q) * E_ + h * HD_ + d] = acc;
}

// ---------------------------------------------------------------------------
// Kernel 3: out = X @ Wo^T + bo.  X: (4096,1024) fp32 ws, Wo: (1024,1024) fp32.
// grid (E/64, NL/64), block 256 (16x16 threads, 4x4 microtile, BK=32).
// ---------------------------------------------------------------------------
__global__ __launch_bounds__(256) void out_gemm_kernel(
    const float* __restrict__ X, const float* __restrict__ Wo,
    const float* __restrict__ bo, float* __restrict__ C)
{
    const int BM = 64, BN = 64, BK = 32;
    __shared__ float sA[BK][BM + 1];  // sA[k][i]
    __shared__ float sB[BK][BN + 1];  // sB[k][j]

    const int j0 = blockIdx.x * BN;
    const int i0 = blockIdx.y * BM;
    const int t  = threadIdx.x;
    const int tx = t & 15, ty = t >> 4;

    float acc[4][4] = {};

    for (int k0 = 0; k0 < E_; k0 += BK) {
        __syncthreads();
        for (int i = t; i < BM * BK; i += 256) {
            int r = i >> 5, c = i & 31;
            sA[c][r] = X[(size_t)(i0 + r) * E_ + k0 + c];
            sB[c][r] = Wo[(size_t)(j0 + r) * E_ + k0 + c];
        }
        __syncthreads();
#pragma unroll
        for (int kk = 0; kk < BK; ++kk) {
            float a[4], b[4];
#pragma unroll
            for (int r = 0; r < 4; ++r) a[r] = sA[kk][ty * 4 + r];
#pragma unroll
            for (int c = 0; c < 4; ++c) b[c] = sB[kk][tx * 4 + c];
#pragma unroll
            for (int r = 0; r < 4; ++r)
#pragma unroll
                for (int c = 0; c < 4; ++c) acc[r][c] += a[r] * b[c];
        }
    }

#pragma unroll
    for (int r = 0; r < 4; ++r) {
        int row = i0 + ty * 4 + r;
#pragma unroll
        for (int c = 0; c < 4; ++c) {
            int col = j0 + tx * 4 + c;
            C[(size_t)row * E_ + col] = acc[r][c] + bo[col];
        }
    }
}

// ---------------------------------------------------------------------------
extern "C" void kernel_launch(void* const* d_in, const int* in_sizes, int n_in,
                              void* d_out, int out_size, void* d_ws, size_t ws_size,
                              hipStream_t stream) {
    const float* values = (const float*)d_in[0];
    const float* keys   = (const float*)d_in[1];
    const float* query  = (const float*)d_in[2];
    const int*   mask   = (const int*)d_in[3];
    const float* Wv     = (const float*)d_in[4];
    const float* Wk     = (const float*)d_in[5];
    const float* Wq     = (const float*)d_in[6];
    const float* Wo     = (const float*)d_in[7];
    const float* bo     = (const float*)d_in[8];
    float* out = (float*)d_out;

    float* ws = (float*)d_ws;
    const size_t M4 = (size_t)N_ * H_ * L_ * HD_;  // 4 Mi elements
    float* v_ws = ws;
    float* k_ws = ws + M4;
    float* q_ws = ws + 2 * M4;
    float* x_ws = ws + 3 * M4;

    proj_kernel<<<dim3(L_ / 64, H_, N_), 256, 0, stream>>>(
        values, keys, query, Wv, Wk, Wq, v_ws, k_ws, q_ws);

    attn_kernel<<<dim3(L_ / TQ, H_, N_), 256, 0, stream>>>(
        q_ws, k_ws, v_ws, mask, x_ws);

    out_gemm_kernel<<<dim3(E_ / 64, (N_ * L_) / 64), 256, 0, stream>>>(
        x_ws, Wo, bo, out);
}

// Round 3
// 267.522 us; speedup vs baseline: 5.6965x; 5.6965x over previous
//
#include <hip/hip_runtime.h>
#include <hip/hip_bf16.h>

#define N_ 4
#define L_ 1024
#define E_ 1024
#define H_ 32
#define HD_ 32

typedef unsigned short ushort;
typedef __attribute__((ext_vector_type(8))) short short8;   // bf16 x8 MFMA A/B frag
typedef __attribute__((ext_vector_type(4))) short short4v;  // bf16 x4 (8B LDS load)
typedef __attribute__((ext_vector_type(4))) float float4v;  // MFMA C/D frag

__device__ __forceinline__ ushort f2b(float f) {
    __hip_bfloat16 h = __float2bfloat16(f);
    return *reinterpret_cast<ushort*>(&h);
}

// ---------------------------------------------------------------------------
// Kernel 1: per-head projections.  Outputs bf16:
//   q_ws,k_ws: (N,H,L,HD)   vt_ws: (N,H,HD,L)  (V transposed for PV B-frags)
// grid (L/64, H, N), block 256.
// ---------------------------------------------------------------------------
__global__ __launch_bounds__(256) void proj_kernel(
    const float* __restrict__ v_in, const float* __restrict__ k_in,
    const float* __restrict__ q_in,
    const float* __restrict__ Wv, const float* __restrict__ Wk,
    const float* __restrict__ Wq,
    ushort* __restrict__ vt_ws, ushort* __restrict__ k_ws,
    ushort* __restrict__ q_ws)
{
    const int TOK = 64;
    const int n = blockIdx.z, h = blockIdx.y, l0 = blockIdx.x * TOK;
    const int t = threadIdx.x;

    __shared__ float sW[3][HD_ * 33];
    __shared__ float sX[TOK][33];

    for (int i = t; i < HD_ * HD_; i += 256) {
        int d = i >> 5, e = i & 31;
        sW[0][d * 33 + e] = Wv[i];
        sW[1][d * 33 + e] = Wk[i];
        sW[2][d * 33 + e] = Wq[i];
    }

    const float* ins[3] = {v_in, k_in, q_in};

    for (int w = 0; w < 3; ++w) {
        __syncthreads();
        for (int i = t; i < TOK * HD_; i += 256) {
            int tok = i >> 5, e = i & 31;
            sX[tok][e] = ins[w][(size_t)(n * L_ + l0 + tok) * E_ + h * HD_ + e];
        }
        __syncthreads();
        if (w == 0) {  // V -> transposed bf16 store (tok contiguous)
            for (int i = t; i < TOK * HD_; i += 256) {
                int d = i >> 6, tok = i & 63;
                float acc = 0.f;
#pragma unroll
                for (int e = 0; e < HD_; ++e) acc += sX[tok][e] * sW[0][d * 33 + e];
                vt_ws[((size_t)((n * H_ + h) * HD_ + d)) * L_ + l0 + tok] = f2b(acc);
            }
        } else {
            ushort* outp = (w == 1) ? k_ws : q_ws;
            for (int i = t; i < TOK * HD_; i += 256) {
                int tok = i >> 5, d = i & 31;
                float acc = 0.f;
#pragma unroll
                for (int e = 0; e < HD_; ++e) acc += sX[tok][e] * sW[w][d * 33 + e];
                outp[((size_t)(n * H_ + h) * L_ + l0 + tok) * HD_ + d] = f2b(acc);
            }
        }
    }
}

// ---------------------------------------------------------------------------
// Kernel 2: flash-style attention, bf16 MFMA.
// grid (L/64, H, N), block 256 (4 waves, 16 q-rows each).
// Per 64-token chunk: QK^T (4 MFMA) -> mask/scale -> online softmax
// (rows in 16-lane quads, 4 rows per lane) -> P via LDS (D->A layout) ->
// PV (4 MFMA) into C-frags.  Output x_ws bf16 (N,L,E).
// ---------------------------------------------------------------------------
__global__ __launch_bounds__(256) void attn_kernel(
    const ushort* __restrict__ q_ws, const ushort* __restrict__ k_ws,
    const ushort* __restrict__ vt_ws, const int* __restrict__ mask,
    ushort* __restrict__ x_ws)
{
    const int n = blockIdx.z, h = blockIdx.y, q0 = blockIdx.x * 64;
    const int t = threadIdx.x;
    const int wave = t >> 6, lane = t & 63;
    const int m = lane & 15, g = lane >> 4;   // col/row-in-frag, quad

    __shared__ ushort sK[64][40];        // [tok][dim], stride 40 -> 2-way banks, 16B aligned
    __shared__ ushort sVt[32][68];       // [dim][tok], stride 68 -> 2-way banks, 8B aligned
    __shared__ ushort sP[4][16][68];     // wave-private P tile [q][tok]
    __shared__ int    sMask[64];

    const int base = (n * H_ + h) * L_;
    const float scale = 0.03125f;        // 1/sqrt(E)=1/32

    // persistent Q A-frag: A[m][k]: row q0+wave*16+m, dims g*8..g*8+7 (16B)
    short8 qfrag = *(const short8*)(q_ws + ((size_t)(base + q0 + wave * 16 + m)) * HD_ + g * 8);

    float m_run[4], l_run[4];
    float4v O[2];
#pragma unroll
    for (int r = 0; r < 4; ++r) { m_run[r] = -3.0e38f; l_run[r] = 0.f; }
    O[0] = float4v{0.f, 0.f, 0.f, 0.f};
    O[1] = float4v{0.f, 0.f, 0.f, 0.f};

    for (int c = 0; c < L_ / 64; ++c) {
        __syncthreads();
        {   // cooperative staging
            int tok = t >> 2, dc = (t & 3) * 8;
            *(short8*)&sK[tok][dc] =
                *(const short8*)(k_ws + ((size_t)(base + c * 64 + tok)) * HD_ + dc);
            int d = t >> 3, tc = (t & 7) * 8;
            const ushort* vsrc = vt_ws + ((size_t)((n * H_ + h) * HD_ + d)) * L_ + c * 64 + tc;
            *(short4v*)&sVt[d][tc]     = *(const short4v*)vsrc;
            *(short4v*)&sVt[d][tc + 4] = *(const short4v*)(vsrc + 4);
            if (t < 64) sMask[t] = mask[n * L_ + c * 64 + t];
        }
        __syncthreads();

        // ---- QK^T: S[16 q][64 tok] as 4 D-frags ----
        float4v S[4];
#pragma unroll
        for (int nb = 0; nb < 4; ++nb) {
            short8 bfrag = *(const short8*)&sK[nb * 16 + m][g * 8];  // B[k=dim][n=tok]
            float4v z = float4v{0.f, 0.f, 0.f, 0.f};
            S[nb] = __builtin_amdgcn_mfma_f32_16x16x32_bf16(qfrag, bfrag, z, 0, 0, 0);
        }
        // mask (before scale, like reference) + scale
#pragma unroll
        for (int nb = 0; nb < 4; ++nb) {
            int mv = sMask[nb * 16 + m];
#pragma unroll
            for (int r = 0; r < 4; ++r)
                S[nb][r] = (mv == 0) ? -3.125e18f : S[nb][r] * scale;
        }
        // ---- online softmax (row r of lane = q row g*4+r; row spans 16 lanes) ----
        float mc[4];
#pragma unroll
        for (int r = 0; r < 4; ++r)
            mc[r] = fmaxf(fmaxf(S[0][r], S[1][r]), fmaxf(S[2][r], S[3][r]));
#pragma unroll
        for (int off = 1; off < 16; off <<= 1)
#pragma unroll
            for (int r = 0; r < 4; ++r)
                mc[r] = fmaxf(mc[r], __shfl_xor(mc[r], off, 64));
        float alpha[4], rs[4];
#pragma unroll
        for (int r = 0; r < 4; ++r) {
            float mn = fmaxf(m_run[r], mc[r]);
            alpha[r] = __expf(m_run[r] - mn);
            m_run[r] = mn;
            rs[r] = 0.f;
        }
#pragma unroll
        for (int nb = 0; nb < 4; ++nb)
#pragma unroll
            for (int r = 0; r < 4; ++r) {
                float p = __expf(S[nb][r] - m_run[r]);
                S[nb][r] = p;
                rs[r] += p;
            }
#pragma unroll
        for (int off = 1; off < 16; off <<= 1)
#pragma unroll
            for (int r = 0; r < 4; ++r)
                rs[r] += __shfl_xor(rs[r], off, 64);
#pragma unroll
        for (int r = 0; r < 4; ++r)
            l_run[r] = l_run[r] * alpha[r] + rs[r];
#pragma unroll
        for (int db = 0; db < 2; ++db)
#pragma unroll
            for (int r = 0; r < 4; ++r)
                O[db][r] *= alpha[r];

        // ---- P: D-layout -> wave-private LDS tile [q][tok] (bf16) ----
#pragma unroll
        for (int nb = 0; nb < 4; ++nb)
#pragma unroll
            for (int r = 0; r < 4; ++r)
                sP[wave][g * 4 + r][nb * 16 + m] = f2b(S[nb][r]);
        // (same-wave LDS RAW: compiler inserts lgkmcnt wait; no barrier needed)

        // ---- PV: O += P(16x64) * V(64x32) ----
#pragma unroll
        for (int kb = 0; kb < 2; ++kb) {
            short4v alo = *(const short4v*)&sP[wave][m][kb * 32 + g * 8];
            short4v ahi = *(const short4v*)&sP[wave][m][kb * 32 + g * 8 + 4];
            short8 afrag = short8{alo[0], alo[1], alo[2], alo[3], ahi[0], ahi[1], ahi[2], ahi[3]};
#pragma unroll
            for (int db = 0; db < 2; ++db) {
                short4v blo = *(const short4v*)&sVt[db * 16 + m][kb * 32 + g * 8];
                short4v bhi = *(const short4v*)&sVt[db * 16 + m][kb * 32 + g * 8 + 4];
                short8 bfrag = short8{blo[0], blo[1], blo[2], blo[3], bhi[0], bhi[1], bhi[2], bhi[3]};
                O[db] = __builtin_amdgcn_mfma_f32_16x16x32_bf16(afrag, bfrag, O[db], 0, 0, 0);
            }
        }
    }

    // ---- epilogue: normalize, write bf16 (N,L,E) ----
#pragma unroll
    for (int r = 0; r < 4; ++r) {
        float inv = 1.f / l_run[r];
        int row = q0 + wave * 16 + g * 4 + r;
#pragma unroll
        for (int db = 0; db < 2; ++db) {
            int col = h * HD_ + db * 16 + m;
            x_ws[((size_t)(n * L_ + row)) * E_ + col] = f2b(O[db][r] * inv);
        }
    }
}

// ---------------------------------------------------------------------------
// Kernel 3: C = X(bf16 4096x1024) @ Wo^T(fp32->bf16) + bo, fp32 out.
// grid (E/64, NL/64), block 256 (4 waves). 64x64 tile, BK=32, MFMA.
// Wave w owns 16 cols; 4 row-frags.
// ---------------------------------------------------------------------------
__global__ __launch_bounds__(256) void out_gemm_kernel(
    const ushort* __restrict__ X, const float* __restrict__ Wo,
    const float* __restrict__ bo, float* __restrict__ C)
{
    const int j0 = blockIdx.x * 64;
    const int i0 = blockIdx.y * 64;
    const int t = threadIdx.x;
    const int wave = t >> 6, lane = t & 63;
    const int m = lane & 15, g = lane >> 4;

    __shared__ ushort sX[64][40];
    __shared__ ushort sW[64][40];

    float4v acc[4];
#pragma unroll
    for (int mb = 0; mb < 4; ++mb) acc[mb] = float4v{0.f, 0.f, 0.f, 0.f};

    for (int k0 = 0; k0 < E_; k0 += 32) {
        __syncthreads();
        {
            int row = t >> 2, kc = (t & 3) * 8;
            *(short8*)&sX[row][kc] =
                *(const short8*)(X + ((size_t)(i0 + row)) * E_ + k0 + kc);
            const float* wsrc = Wo + ((size_t)(j0 + row)) * E_ + k0 + kc;
            float4v w0 = *(const float4v*)wsrc;
            float4v w1 = *(const float4v*)(wsrc + 4);
            short8 wfrag = short8{(short)f2b(w0[0]), (short)f2b(w0[1]),
                                  (short)f2b(w0[2]), (short)f2b(w0[3]),
                                  (short)f2b(w1[0]), (short)f2b(w1[1]),
                                  (short)f2b(w1[2]), (short)f2b(w1[3])};
            *(short8*)&sW[row][kc] = wfrag;
        }
        __syncthreads();
        short8 bfrag = *(const short8*)&sW[wave * 16 + m][g * 8];  // B[k][n=col]
#pragma unroll
        for (int mb = 0; mb < 4; ++mb) {
            short8 afrag = *(const short8*)&sX[mb * 16 + m][g * 8];
            acc[mb] = __builtin_amdgcn_mfma_f32_16x16x32_bf16(afrag, bfrag, acc[mb], 0, 0, 0);
        }
    }

    int col = j0 + wave * 16 + m;
    float bias = bo[col];
#pragma unroll
    for (int mb = 0; mb < 4; ++mb)
#pragma unroll
        for (int r = 0; r < 4; ++r) {
            int row = i0 + mb * 16 + g * 4 + r;
            C[(size_t)row * E_ + col] = acc[mb][r] + bias;
        }
}

// ---------------------------------------------------------------------------
extern "C" void kernel_launch(void* const* d_in, const int* in_sizes, int n_in,
                              void* d_out, int out_size, void* d_ws, size_t ws_size,
                              hipStream_t stream) {
    const float* values = (const float*)d_in[0];
    const float* keys   = (const float*)d_in[1];
    const float* query  = (const float*)d_in[2];
    const int*   mask   = (const int*)d_in[3];
    const float* Wv     = (const float*)d_in[4];
    const float* Wk     = (const float*)d_in[5];
    const float* Wq     = (const float*)d_in[6];
    const float* Wo     = (const float*)d_in[7];
    const float* bo     = (const float*)d_in[8];
    float* out = (float*)d_out;

    const size_t M4 = (size_t)N_ * H_ * L_ * HD_;  // 4 Mi elements
    ushort* q_ws  = (ushort*)d_ws;
    ushort* k_ws  = q_ws + M4;
    ushort* vt_ws = k_ws + M4;
    ushort* x_ws  = vt_ws + M4;

    proj_kernel<<<dim3(L_ / 64, H_, N_), 256, 0, stream>>>(
        values, keys, query, Wv, Wk, Wq, vt_ws, k_ws, q_ws);

    attn_kernel<<<dim3(L_ / 64, H_, N_), 256, 0, stream>>>(
        q_ws, k_ws, vt_ws, mask, x_ws);

    out_gemm_kernel<<<dim3(E_ / 64, (N_ * L_) / 64), 256, 0, stream>>>(
        x_ws, Wo, bo, out);
}